// Round 9
// baseline (114.867 us; speedup 1.0000x reference)
//
#include <hip/hip_runtime.h>

#define NB   4
#define CO   16
#define PH   7
#define PW   7
#define SR   2
#define HH   80
#define WW   80
#define NROI 512
#define CIJ  (CO*PH*PW)   // 784
#define PLANE (HH*WW)     // 6400 floats = 25.6 KB
#define NF4  (PLANE/4)    // 1600

typedef float f4v __attribute__((ext_vector_type(4), aligned(16)));

typedef __attribute__((address_space(1))) const void gvoid_t;
typedef __attribute__((address_space(3))) void svoid_t;

// d_ws layout:
//   [0]     int   base[8]
//   [64]    u16   order[512]
//   [2048]  f4v   geom[512]     (x1, y1, bin_w, bin_h)
//   [16384] float out_t[CIJ*NROI]  (transposed result, 1.6 MB)
#define WS_ORDER_OFF 64
#define WS_GEOM_OFF  2048
#define WS_OUTT_OFF  16384

// ---- prep: compact ROIs by batch, precompute geometry (1 block) ----
__global__ __launch_bounds__(512) void psroi_prep_kernel(
    const float* __restrict__ rois, int* __restrict__ base,
    unsigned short* __restrict__ order, f4v* __restrict__ geom)
{
    __shared__ int cnt[NB];
    __shared__ int cbase[NB + 1];
    int n = threadIdx.x;
    if (n < NB) cnt[n] = 0;
    __syncthreads();
    int b = (int)rois[n * 5 + 0];
    int rank = atomicAdd(&cnt[b], 1);
    __syncthreads();
    if (n == 0) {
        cbase[0] = 0;
        for (int k = 0; k < NB; ++k) cbase[k + 1] = cbase[k] + cnt[k];
        for (int k = 0; k <= NB; ++k) base[k] = cbase[k];
    }
    __syncthreads();
    int pos = cbase[b] + rank;
    order[pos] = (unsigned short)n;

    float x1 = rois[n * 5 + 1] * (float)WW;
    float y1 = rois[n * 5 + 2] * (float)HH;
    float x2 = rois[n * 5 + 3] * (float)WW;
    float y2 = rois[n * 5 + 4] * (float)HH;
    f4v g;
    g.x = x1;
    g.y = y1;
    g.z = fmaxf(x2 - x1, 0.1f) * (1.0f / PW);   // bin_w
    g.w = fmaxf(y2 - y1, 0.1f) * (1.0f / PH);   // bin_h
    geom[pos] = g;
}

// ---- main: one block per (cij,b); stage plane via global_load_lds DMA,
// pair-split gather, COALESCED store to transposed out_t[cij*512 + p]. ----
__global__ __launch_bounds__(256) void psroi_main_kernel(
    const float* __restrict__ feat,
    const int* __restrict__ base,
    const f4v* __restrict__ geom,
    float* __restrict__ out_t)        // [CIJ, NROI]
{
    __shared__ __align__(16) float sp[PLANE];

    int u   = blockIdx.x;       // cij*4 + b
    int cij = u >> 2;
    int b   = u & 3;
    int rem = cij % (PH * PW);
    int i = rem / PW;
    int j = rem % PW;
    int n = threadIdx.x;

    // stage plane (b, cij): 16B-wide DMA, no VGPR round-trip
    const f4v* src = (const f4v*)(feat + ((size_t)b * CIJ + (size_t)cij) * PLANE);
    int wbase = n & ~63;
    #pragma unroll
    for (int it = 0; it < 6; ++it) {
        const f4v* g = src + it * 256 + n;
        float* l = sp + (size_t)(it * 256 + wbase) * 4;
        __builtin_amdgcn_global_load_lds((gvoid_t*)g, (svoid_t*)l, 16, 0, 0);
    }
    if (n < 64) {
        const f4v* g = src + 1536 + n;
        float* l = sp + (size_t)1536 * 4;
        __builtin_amdgcn_global_load_lds((gvoid_t*)g, (svoid_t*)l, 16, 0, 0);
    }

    int lo = base[b];
    int hi = base[b + 1];
    int count = hi - lo;

    __syncthreads();            // DMA drained

    int sy = n & 1;
    float sy_off = ((float)sy + 0.5f) * (1.0f / SR);

    for (int t = (n >> 1); t < count; t += 128) {
        f4v g = geom[lo + t];
        float x1 = g.x, y1 = g.y, bin_w = g.z, bin_h = g.w;

        float ys = y1 + ((float)i + sy_off) * bin_h;
        bool ymask = (ys >= -1.0f) && (ys <= (float)HH);
        float yc = fminf(fmaxf(ys, 0.0f), (float)(HH - 1));
        int   y0 = (int)floorf(yc);
        int   y1i = min(y0 + 1, HH - 1);
        float ly = yc - (float)y0, hy = 1.0f - ly;

        float partial = 0.0f;
        #pragma unroll
        for (int sx = 0; sx < SR; ++sx) {
            float xs = x1 + ((float)j + ((float)sx + 0.5f) * (1.0f / SR)) * bin_w;
            bool xmask = (xs >= -1.0f) && (xs <= (float)WW);
            float xc = fminf(fmaxf(xs, 0.0f), (float)(WW - 1));
            int   x0 = (int)floorf(xc);
            int   x0c = min(x0, WW - 2);   // x0==79 -> lx==0, shifted pair exact
            bool  sh = (x0 != x0c);
            float lx = xc - (float)x0, hx = 1.0f - lx;

            float t0 = sp[y0  * WW + x0c], t1 = sp[y0  * WW + x0c + 1];
            float b0 = sp[y1i * WW + x0c], b1 = sp[y1i * WW + x0c + 1];

            float v00 = sh ? t1 : t0;
            float v10 = sh ? b1 : b0;
            float v = (v00 * hx + t1 * lx) * hy + (v10 * hx + b1 * lx) * ly;
            if (ymask && xmask) partial += v;
        }

        float other = __shfl_xor(partial, 1);
        if (sy == 0)
            out_t[(size_t)cij * NROI + lo + t] = (partial + other) * 0.25f;
    }
}

// ---- transpose: out_t[cij, p] -> out[order[p]*CIJ + cij] via LDS tile ----
// tile: 16 cij x 64 p. Grid 49*8 = 392 blocks of 256.
// Writes are aligned full 64B lines (m*3136 is 64B-aligned, 16 cij = 64B).
__global__ __launch_bounds__(256) void psroi_tr_kernel(
    const float* __restrict__ out_t,
    const unsigned short* __restrict__ order,
    float* __restrict__ out)
{
    __shared__ float tile[64][17];   // [p][cij], pad -> conflict-free

    int gx = blockIdx.x % 49;        // cij tile
    int gp = blockIdx.x / 49;        // p tile
    int cij0 = gx * 16;
    int p0 = gp * 64;
    int tid = threadIdx.x;

    int c  = tid & 63;               // p offset
    int r4 = tid >> 6;               // 0..3
    #pragma unroll
    for (int rr = 0; rr < 4; ++rr) {
        int r = r4 * 4 + rr;         // cij offset 0..15
        tile[c][r] = out_t[(size_t)(cij0 + r) * NROI + p0 + c];
    }
    __syncthreads();

    int cj = tid & 15;               // cij offset
    int pq = tid >> 4;               // 0..15
    #pragma unroll
    for (int ch = 0; ch < 4; ++ch) {
        int pp = ch * 16 + pq;       // p offset 0..63
        int m = (int)order[p0 + pp];
        out[(size_t)m * CIJ + cij0 + cj] = tile[pp][cj];
    }
}

extern "C" void kernel_launch(void* const* d_in, const int* in_sizes, int n_in,
                              void* d_out, int out_size, void* d_ws, size_t ws_size,
                              hipStream_t stream)
{
    const float* feat = (const float*)d_in[0];
    const float* rois = (const float*)d_in[1];
    float* out = (float*)d_out;

    char* ws = (char*)d_ws;
    int* base = (int*)ws;
    unsigned short* order = (unsigned short*)(ws + WS_ORDER_OFF);
    f4v* geom = (f4v*)(ws + WS_GEOM_OFF);
    float* out_t = (float*)(ws + WS_OUTT_OFF);

    psroi_prep_kernel<<<1, NROI, 0, stream>>>(rois, base, order, geom);
    psroi_main_kernel<<<CIJ * NB, 256, 0, stream>>>(feat, base, geom, out_t);
    psroi_tr_kernel<<<49 * 8, 256, 0, stream>>>(out_t, order, out);
}